// Round 9
// baseline (756.985 us; speedup 1.0000x reference)
//
#include <hip/hip_runtime.h>
#include <math.h>

typedef __bf16 bf16_t;
typedef __bf16 bf8v __attribute__((ext_vector_type(8)));
typedef __bf16 bf4v __attribute__((ext_vector_type(4)));
typedef float  f4v  __attribute__((ext_vector_type(4)));

#define BB  8
#define CC  512
#define NN  4096
#define CPG 16
#define NCb (NN * CC)
#define WSZ (CC * CC)

#define FLG_SIZES 805306368.f
#define FLG_WS    536870912.f

__global__ void diag_out(float* out, float v) { if (threadIdx.x == 0) out[0] = v; }

// async global->LDS, 16B per lane; LDS dest is wave-uniform base + lane*16.
__device__ __forceinline__ void gload_lds16(const bf16_t* g, bf16_t* l)
{
    __builtin_amdgcn_global_load_lds(
        (const __attribute__((address_space(1))) unsigned int*)g,
        (__attribute__((address_space(3))) unsigned int*)l, 16, 0, 0);
}

// ---------------------------------------------------------------------------
// Convert the four 512x512 fp32 weights to bf16, packed [Wq|Wk|Wv|Wo].
// ---------------------------------------------------------------------------
__global__ __launch_bounds__(256) void cvt_w(const float* __restrict__ a,
                                             const float* __restrict__ b,
                                             const float* __restrict__ c,
                                             const float* __restrict__ d,
                                             bf16_t* __restrict__ o)
{
    const int i = (blockIdx.x * 256 + threadIdx.x) * 4;
    const float* srcs[4] = {a, b, c, d};
#pragma unroll
    for (int m = 0; m < 4; m++) {
        float4 v = *(const float4*)(srcs[m] + i);
        bf4v w;
        w[0] = (bf16_t)v.x; w[1] = (bf16_t)v.y;
        w[2] = (bf16_t)v.z; w[3] = (bf16_t)v.w;
        *(bf4v*)(o + (size_t)m * WSZ + i) = w;
    }
}

// ---------------------------------------------------------------------------
// GroupNorm stats, two-stage (1024 partial blocks + 1 finish block).
// ---------------------------------------------------------------------------
__global__ __launch_bounds__(256) void gn_stats_part(const float* __restrict__ x,
                                                     double* __restrict__ part)
{
    const int bg = blockIdx.x >> 2;
    const int sl = blockIdx.x & 3;
    const int tid = threadIdx.x;
    const float4* xv = (const float4*)(x + (size_t)bg * CPG * NN) + sl * 4096;
    double s[4] = {0, 0, 0, 0}, ss[4] = {0, 0, 0, 0};
#pragma unroll
    for (int ii = 0; ii < 16; ii++) {
        float4 v = xv[tid + ii * 256];
        const int a = ii & 3;
        s[a]  += (double)v.x + (double)v.y + (double)v.z + (double)v.w;
        ss[a] += (double)v.x * v.x + (double)v.y * v.y
               + (double)v.z * v.z + (double)v.w * v.w;
    }
    double sT = s[0] + s[1] + s[2] + s[3];
    double ssT = ss[0] + ss[1] + ss[2] + ss[3];
    __shared__ double l1[256], l2[256];
    l1[tid] = sT; l2[tid] = ssT;
    __syncthreads();
    for (int o = 128; o > 0; o >>= 1) {
        if (tid < o) { l1[tid] += l1[tid + o]; l2[tid] += l2[tid + o]; }
        __syncthreads();
    }
    if (tid == 0) {
        part[(size_t)blockIdx.x * 2]     = l1[0];
        part[(size_t)blockIdx.x * 2 + 1] = l2[0];
    }
}

__global__ __launch_bounds__(256) void gn_stats_fin(const double* __restrict__ part,
                                                    float* __restrict__ stats)
{
    const int bg = threadIdx.x;          // 0..255
    double s = 0.0, ss = 0.0;
#pragma unroll
    for (int sl = 0; sl < 4; sl++) {
        s  += part[(size_t)(bg * 4 + sl) * 2];
        ss += part[(size_t)(bg * 4 + sl) * 2 + 1];
    }
    double mean = s * (1.0 / 65536.0);
    double var  = ss * (1.0 / 65536.0) - mean * mean;
    stats[bg * 2]     = (float)mean;
    stats[bg * 2 + 1] = (float)(1.0 / sqrt(var + 1e-6));
}

// ---------------------------------------------------------------------------
// GN apply, ALL batches: x (B,C,N) fp32 -> h_all (B,N,C) bf16. grid (512, 8).
// ---------------------------------------------------------------------------
__global__ __launch_bounds__(256) void gn_apply_all(const float* __restrict__ x,
                                                    const float* __restrict__ gw,
                                                    const float* __restrict__ gb,
                                                    const float* __restrict__ stats,
                                                    bf16_t* __restrict__ h_all)
{
    const int b  = blockIdx.y;
    const int g  = blockIdx.x >> 4;
    const int sl = blockIdx.x & 15;
    const float* xp = x + (size_t)b * CC * NN + (size_t)g * CPG * NN;
    bf16_t* h = h_all + (size_t)b * NCb;
    const int tid = threadIdx.x;
    const float mean = stats[(b * 32 + g) * 2];
    const float rstd = stats[(b * 32 + g) * 2 + 1];
    const int cw = tid & 15;
    const float aa = rstd * gw[g * CPG + cw];
    const float bb = gb[g * CPG + cw] - mean * aa;

    __shared__ float tile[CPG][260];
    const int n0 = sl * 256;
    for (int i = tid; i < (CPG * 256) / 4; i += 256) {
        int c  = i >> 6;
        int n4 = i & 63;
        float4 v = *(const float4*)(xp + (size_t)c * NN + n0 + n4 * 4);
        tile[c][n4 * 4 + 0] = v.x;
        tile[c][n4 * 4 + 1] = v.y;
        tile[c][n4 * 4 + 2] = v.z;
        tile[c][n4 * 4 + 3] = v.w;
    }
    __syncthreads();
#pragma unroll
    for (int j = 0; j < 16; j++) {
        int n = (tid >> 4) + 16 * j;
        float v = tile[cw][n] * aa + bb;
        h[(size_t)(n0 + n) * CC + g * CPG + cw] = (bf16_t)v;
    }
}

// ---------------------------------------------------------------------------
// GN apply for one batch (fallback path).
// ---------------------------------------------------------------------------
__global__ __launch_bounds__(256) void gn_apply(const float* __restrict__ xb,
                                                const float* __restrict__ gw,
                                                const float* __restrict__ gb,
                                                const float* __restrict__ stats,
                                                bf16_t* __restrict__ h,
                                                int bg0)
{
    const int g  = blockIdx.x >> 4;
    const int sl = blockIdx.x & 15;
    const float* xp = xb + (size_t)g * CPG * NN;
    const int tid = threadIdx.x;
    const float mean = stats[(bg0 + g) * 2];
    const float rstd = stats[(bg0 + g) * 2 + 1];
    const int cw = tid & 15;
    const float aa = rstd * gw[g * CPG + cw];
    const float bb = gb[g * CPG + cw] - mean * aa;

    __shared__ float tile[CPG][260];
    const int n0 = sl * 256;
    for (int i = tid; i < (CPG * 256) / 4; i += 256) {
        int c  = i >> 6;
        int n4 = i & 63;
        float4 v = *(const float4*)(xp + (size_t)c * NN + n0 + n4 * 4);
        tile[c][n4 * 4 + 0] = v.x;
        tile[c][n4 * 4 + 1] = v.y;
        tile[c][n4 * 4 + 2] = v.z;
        tile[c][n4 * 4 + 3] = v.w;
    }
    __syncthreads();
#pragma unroll
    for (int j = 0; j < 16; j++) {
        int n = (tid >> 4) + 16 * j;
        float v = tile[cw][n] * aa + bb;
        h[(size_t)(n0 + n) * CC + g * CPG + cw] = (bf16_t)v;
    }
}

// ===========================================================================
// OLD 4-wave 128x256 core (fallback path only).
// ===========================================================================
#define ABUF (128 * 32)
#define BBUF (256 * 32)
#define NBUF 3

__device__ __forceinline__ void stage_tile(
    const bf16_t* pa, const bf16_t* pb, int lda, int ldb,
    bf16_t* lA, bf16_t* lB)
{
    gload_lds16(pa,                     lA);
    gload_lds16(pa + (size_t)16 * lda,  lA + 16 * 32);
    gload_lds16(pb,                     lB);
    gload_lds16(pb + (size_t)16 * ldb,  lB + 16 * 32);
    gload_lds16(pb + (size_t)32 * ldb,  lB + 32 * 32);
    gload_lds16(pb + (size_t)48 * ldb,  lB + 48 * 32);
}

__device__ __forceinline__ void gemm_core_w(
    const bf16_t* __restrict__ A, const bf16_t* __restrict__ B,
    int K, int lda, int ldb, size_t m0, size_t n0,
    bf16_t* Asm, bf16_t* Bsm,
    int wave, int lane, int wm, int wn, int fr, int fq, f4v acc[4][8])
{
    const int gr  = lane >> 2;
    const int gcs = (((lane & 3) ^ (gr & 3)) << 3);
    const bf16_t* pa = A + (m0 + wave * 32 + gr) * lda + gcs;
    const bf16_t* pb = B + (n0 + wave * 64 + gr) * ldb + gcs;
    const int la0 = (wave * 32) * 32;
    const int lb0 = (wave * 64) * 32;
    const int fqs = ((fq ^ (fr & 3)) << 3);

    stage_tile(pa, pb, lda, ldb, Asm + la0, Bsm + lb0);
    if (K > 32)
        stage_tile(pa + 32, pb + 32, lda, ldb,
                   Asm + ABUF + la0, Bsm + BBUF + lb0);

    int buf = 0;
    for (int kt = 0; kt < K; kt += 32) {
        if (kt + 64 < K) {
            const int nb = (buf + 2 >= NBUF) ? buf + 2 - NBUF : buf + 2;
            stage_tile(pa + kt + 64, pb + kt + 64, lda, ldb,
                       Asm + nb * ABUF + la0, Bsm + nb * BBUF + lb0);
            asm volatile("s_waitcnt vmcnt(12)" ::: "memory");
        } else if (kt + 32 < K) {
            asm volatile("s_waitcnt vmcnt(6)" ::: "memory");
        } else {
            asm volatile("s_waitcnt vmcnt(0)" ::: "memory");
        }
        __builtin_amdgcn_s_barrier();

        const bf16_t* As = Asm + buf * ABUF;
        const bf16_t* Bs = Bsm + buf * BBUF;
        bf8v af[4], bfv[8];
#pragma unroll
        for (int j = 0; j < 8; j++)
            bfv[j] = *(const bf8v*)(Bs + (wn + j * 16 + fr) * 32 + fqs);
#pragma unroll
        for (int i = 0; i < 4; i++)
            af[i] = *(const bf8v*)(As + (wm + i * 16 + fr) * 32 + fqs);
#pragma unroll
        for (int i = 0; i < 4; i++)
#pragma unroll
            for (int j = 0; j < 8; j++)
                acc[i][j] = __builtin_amdgcn_mfma_f32_16x16x32_bf16(
                    af[i], bfv[j], acc[i][j], 0, 0, 0);

        __builtin_amdgcn_s_barrier();
        buf = (buf + 1 == NBUF) ? 0 : buf + 1;
    }
}

// old-style kernels kept for the small-workspace fallback path
template <int MODE>
__global__ __launch_bounds__(256, 2) void gemm_bt(
    const bf16_t* __restrict__ A, const bf16_t* __restrict__ B,
    void* __restrict__ Og, const float* __restrict__ bias,
    const float* __restrict__ resid, float scale,
    int K, int lda, int ldb, int ldo)
{
    __shared__ bf16_t Asm[NBUF * ABUF];
    __shared__ bf16_t Bsm[NBUF * BBUF];
    const int tid  = threadIdx.x;
    const int lane = tid & 63, wave = tid >> 6;
    const int wm = (wave >> 1) << 6, wn = (wave & 1) << 7;
    const int fr = lane & 15, fq = lane >> 4;
    const size_t m0 = (size_t)blockIdx.x * 128, n0 = (size_t)blockIdx.y * 256;

    f4v acc[4][8];
#pragma unroll
    for (int i = 0; i < 4; i++)
#pragma unroll
        for (int j = 0; j < 8; j++) acc[i][j] = (f4v){0.f, 0.f, 0.f, 0.f};

    gemm_core_w(A, B, K, lda, ldb, m0, n0, Asm, Bsm,
                wave, lane, wm, wn, fr, fq, acc);

    if (MODE == 0) {
        bf16_t* out = (bf16_t*)Og;
#pragma unroll
        for (int i = 0; i < 4; i++) {
            const int mb = (int)m0 + wm + i * 16 + fq * 4;
#pragma unroll
            for (int j = 0; j < 8; j++) {
                const int n = (int)n0 + wn + j * 16 + fr;
                const float bn = bias ? bias[n] : 0.f;
#pragma unroll
                for (int t = 0; t < 4; t++)
                    out[(size_t)(mb + t) * ldo + n] =
                        (bf16_t)(acc[i][j][t] * scale + bn);
            }
        }
    } else {
        float* out = (float*)Og;
#pragma unroll
        for (int i = 0; i < 4; i++) {
            const int mb = (int)m0 + wm + i * 16 + fq * 4;
#pragma unroll
            for (int j = 0; j < 8; j++) {
                const int n = (int)n0 + wn + j * 16 + fr;
                const float bn = bias[n];
                float4 rq = *(const float4*)(resid + (size_t)n * ldo + mb);
                float4 o4;
                o4.x = acc[i][j][0] * scale + bn + rq.x;
                o4.y = acc[i][j][1] * scale + bn + rq.y;
                o4.z = acc[i][j][2] * scale + bn + rq.z;
                o4.w = acc[i][j][3] * scale + bn + rq.w;
                *(float4*)(out + (size_t)n * ldo + mb) = o4;
            }
        }
    }
}

__global__ __launch_bounds__(256, 2) void gemm_qkv(
    const bf16_t* __restrict__ h, const bf16_t* __restrict__ Wb,
    const float* __restrict__ bq, const float* __restrict__ bk,
    const float* __restrict__ bv,
    bf16_t* __restrict__ q, bf16_t* __restrict__ k, bf16_t* __restrict__ v)
{
    __shared__ bf16_t Asm[NBUF * ABUF];
    __shared__ bf16_t Bsm[NBUF * BBUF];
    const int z = blockIdx.z;
    const bf16_t* B = Wb + (size_t)z * WSZ;
    const float* bias = (z == 0) ? bq : (z == 1) ? bk : bv;
    bf16_t* out = (z == 0) ? q : (z == 1) ? k : v;

    const int tid  = threadIdx.x;
    const int lane = tid & 63, wave = tid >> 6;
    const int wm = (wave >> 1) << 6, wn = (wave & 1) << 7;
    const int fr = lane & 15, fq = lane >> 4;
    const size_t m0 = (size_t)blockIdx.x * 128, n0 = (size_t)blockIdx.y * 256;

    f4v acc[4][8];
#pragma unroll
    for (int i = 0; i < 4; i++)
#pragma unroll
        for (int j = 0; j < 8; j++) acc[i][j] = (f4v){0.f, 0.f, 0.f, 0.f};

    gemm_core_w(h, B, 512, 512, 512, m0, n0, Asm, Bsm,
                wave, lane, wm, wn, fr, fq, acc);

    if (z < 2) {
#pragma unroll
        for (int i = 0; i < 4; i++) {
            const int mb = (int)m0 + wm + i * 16 + fq * 4;
#pragma unroll
            for (int j = 0; j < 8; j++) {
                const int n = (int)n0 + wn + j * 16 + fr;
                const float bn = bias[n];
#pragma unroll
                for (int t = 0; t < 4; t++)
                    out[(size_t)(mb + t) * 512 + n] =
                        (bf16_t)(acc[i][j][t] + bn);
            }
        }
    } else {
#pragma unroll
        for (int i = 0; i < 4; i++) {
            const int mb = (int)m0 + wm + i * 16 + fq * 4;
#pragma unroll
            for (int j = 0; j < 8; j++) {
                const int n = (int)n0 + wn + j * 16 + fr;
                const float bn = bias[n];
                bf4v pk;
#pragma unroll
                for (int t = 0; t < 4; t++)
                    pk[t] = (bf16_t)(acc[i][j][t] + bn);
                *(bf4v*)(out + (size_t)n * NN + mb) = pk;
            }
        }
    }
}

__global__ __launch_bounds__(256, 2) void gemm_pv_split(
    const bf16_t* __restrict__ A, const bf16_t* __restrict__ B,
    float* __restrict__ P, int KS)
{
    __shared__ bf16_t Asm[NBUF * ABUF];
    __shared__ bf16_t Bsm[NBUF * BBUF];
    const int tid  = threadIdx.x;
    const int lane = tid & 63, wave = tid >> 6;
    const int wm = (wave >> 1) << 6, wn = (wave & 1) << 7;
    const int fr = lane & 15, fq = lane >> 4;
    const size_t m0 = (size_t)blockIdx.x * 128, n0 = (size_t)blockIdx.y * 256;
    const int z  = blockIdx.z;
    const int k0 = z * KS;

    f4v acc[4][8];
#pragma unroll
    for (int i = 0; i < 4; i++)
#pragma unroll
        for (int j = 0; j < 8; j++) acc[i][j] = (f4v){0.f, 0.f, 0.f, 0.f};

    gemm_core_w(A + k0, B + k0, KS, NN, NN, m0, n0, Asm, Bsm,
                wave, lane, wm, wn, fr, fq, acc);

    float* out = P + (size_t)z * NCb;
#pragma unroll
    for (int i = 0; i < 4; i++) {
        const int mb = (int)m0 + wm + i * 16 + fq * 4;
#pragma unroll
        for (int j = 0; j < 8; j++) {
            const int n = (int)n0 + wn + j * 16 + fr;
#pragma unroll
            for (int t = 0; t < 4; t++)
                out[(size_t)(mb + t) * CC + n] = acc[i][j][t];
        }
    }
}

__global__ __launch_bounds__(256) void pv_reduce(const float* __restrict__ P,
                                                 bf16_t* __restrict__ O, int NS)
{
    const size_t i = ((size_t)blockIdx.x * 256 + threadIdx.x) * 4;
    float4 s = *(const float4*)(P + i);
    for (int z = 1; z < NS; z++) {
        float4 t = *(const float4*)(P + (size_t)z * NCb + i);
        s.x += t.x; s.y += t.y; s.z += t.z; s.w += t.w;
    }
    bf4v o;
    o[0] = (bf16_t)s.x; o[1] = (bf16_t)s.y;
    o[2] = (bf16_t)s.z; o[3] = (bf16_t)s.w;
    *(bf4v*)(O + i) = o;
}

// ===========================================================================
// 256x256 8-wave 8-phase GEMM core (m201 template, plain HIP).
// Round-9 change: swizzle seed r&3 -> (r>>1)&3. With 64B rows, bank_start =
// (fr*16 + (fq^s(fr))*4) mod 32. s=fr&3 repeats every 4 lanes -> 4-way
// conflict (x1.58, m136) on the LDS-BW-limited phase floor (~32-64KB
// read/phase at 128B/cy). s=(fr>>1)&3 yields 8 distinct 4-bank groups, each
// exactly 2x across 16 lanes -> 2-way = free (1.02x). Applied BOTH sides
// (rule #21): stage source uses s=(srow>>1)&3, read uses s=(fr>>1)&3; all
// row bases are multiples of 16, so the permutation is identical/bijective.
// ===========================================================================
#define SL8 8192   // bf16 elems per slot (256 x 32)

__device__ __forceinline__ void stage_g(const bf16_t* g, int ld, bf16_t* slot,
                                        int r0, int srow, int schk)
{
    gload_lds16(g + (size_t)(r0 + srow) * ld + schk,      slot + r0 * 32);
    gload_lds16(g + (size_t)(r0 + 16 + srow) * ld + schk, slot + (r0 + 16) * 32);
}

__device__ __forceinline__ void rd4(bf8v* dst, const bf16_t* slot, int base,
                                    int fr, int rchk)
{
#pragma unroll
    for (int i = 0; i < 4; i++)
        dst[i] = *(const bf8v*)(slot + (base + i * 16 + fr) * 32 + rchk);
}

template <int IH>
__device__ __forceinline__ void mma16(const bf8v* af, const bf8v* bfv,
                                      f4v (&acc)[8][4])
{
    __builtin_amdgcn_s_setprio(1);
#pragma unroll
    for (int i = 0; i < 4; i++)
#pragma unroll
        for (int j = 0; j < 4; j++)
            acc[IH * 4 + i][j] = __builtin_amdgcn_mfma_f32_16x16x32_bf16(
                af[i], bfv[j], acc[IH * 4 + i][j], 0, 0, 0);
    __builtin_amdgcn_s_setprio(0);
}

#define FENCE8 asm volatile("" ::: "memory")
#define BAR8   do { FENCE8; __builtin_amdgcn_s_barrier(); FENCE8; } while (0)

__device__ __forceinline__ void gemm_core8(
    const bf16_t* __restrict__ A, const bf16_t* __restrict__ B,
    int K, int lda, int ldb, size_t m0, size_t n0,
    bf16_t* lds, f4v (&acc)[8][4])
{
    const int tid  = threadIdx.x;
    const int lane = tid & 63, wave = tid >> 6;
    const int wm2 = wave >> 2, wn4 = wave & 3;
    const int fr = lane & 15, fq = lane >> 4;
    const int srow = lane >> 2;
    const int schk = ((lane & 3) ^ ((srow >> 1) & 3)) << 3;   // elems
    const int r0   = wave * 32;
    const int rchk = ((fq ^ ((fr >> 1) & 3)) << 3);           // elems

    const bf16_t* Ag = A + m0 * lda;
    const bf16_t* Bg = B + n0 * ldb;
    const int NT = K >> 6;                             // K-tiles (>=2, even)

    bf16_t* S0 = lds;
    bf16_t* S1 = lds + 1 * SL8;
    bf16_t* S2 = lds + 2 * SL8;
    bf16_t* S3 = lds + 3 * SL8;
    bf16_t* S4 = lds + 4 * SL8;
    bf16_t* S5 = lds + 5 * SL8;
    bf16_t* S6 = lds + 6 * SL8;
    bf16_t* S7 = lds + 7 * SL8;

    const int abase = wm2 * 128;
    const int bbase = wn4 * 64;

    // prologue: T0 {Aks0,Aks1,Bks0,Bks1}, T1 {Bks0,Aks0,Bks1}  (14 loads)
    stage_g(Ag,      lda, S0, r0, srow, schk);
    stage_g(Ag + 32, lda, S1, r0, srow, schk);
    stage_g(Bg,      ldb, S2, r0, srow, schk);
    stage_g(Bg + 32, ldb, S3, r0, srow, schk);
    stage_g(Bg + 64, ldb, S6, r0, srow, schk);
    stage_g(Ag + 64, lda, S4, r0, srow, schk);
    stage_g(Bg + 96, ldb, S7, r0, srow, schk);
    asm volatile("s_waitcnt vmcnt(6)" ::: "memory");
    __builtin_amdgcn_s_barrier();
    FENCE8;

    bf8v af[4], bfv[4];
    const int iters = NT >> 1;
    for (int it = 0; it < iters; it++) {
        const int t1k = (2 * it + 1) << 6;
        const int t2k = (2 * it + 2) << 6;
        const int t3k = (2 * it + 3) << 6;
        const bool s23 = (2 * it + 2) < NT;   // NT even => t2,t3 guard equal

        // ph1: T(2it) (ks0,ih0) buf0; stage A-ks1(2it+1) -> S5
        rd4(af, S0, abase, fr, rchk);
        rd4(bfv, S2, bbase, fr, rchk);
        stage_g(Ag + t1k + 32, lda, S5, r0, srow, schk);
        BAR8; mma16<0>(af, bfv, acc); BAR8;

        // ph2: (ks0,ih1); stage B-ks0(t2) -> S2
        rd4(af, S0, abase + 64, fr, rchk);
        if (s23) stage_g(Bg + t2k, ldb, S2, r0, srow, schk);
        BAR8; mma16<1>(af, bfv, acc); BAR8;

        // ph3: (ks1,ih0); stage A-ks0(t2) -> S0
        rd4(af, S1, abase, fr, rchk);
        rd4(bfv, S3, bbase, fr, rchk);
        if (s23) stage_g(Ag + t2k, lda, S0, r0, srow, schk);
        BAR8; mma16<0>(af, bfv, acc); BAR8;

        // ph4: (ks1,ih1); stage B-ks1(t2) -> S3; vmcnt
        rd4(af, S1, abase + 64, fr, rchk);
        if (s23) {
            stage_g(Bg + t2k + 32, ldb, S3, r0, srow, schk);
            asm volatile("s_waitcnt vmcnt(6)" ::: "memory");
        } else {
            asm volatile("s_waitcnt vmcnt(0)" ::: "memory");
        }
        BAR8; mma16<1>(af, bfv, acc); BAR8;

        // ph5: T(2it+1) (ks0,ih0) buf1; stage A-ks1(t2) -> S1
        rd4(af, S4, abase, fr, rchk);
        rd4(bfv, S6, bbase, fr, rchk);
        if (s23) stage_g(Ag + t2k + 32, lda, S1, r0, srow, schk);
        BAR8; mma16<0>(af, bfv, acc); BAR8;

        // ph6: (ks0,ih1); stage B-ks0(t3) -> S6
        rd4(af, S4, abase + 64, fr, rchk);
        if (s23) stage_g(Bg + t3k, ldb, S6, r0, srow, schk);
        BAR8; mma16<1>(af, bfv, acc); BAR8;

        // ph7: (ks1,ih0); stage A-ks0(t3) -> S4
        rd4(af, S5, abase, fr, rchk);
        rd4(bfv, S7, bbase, fr, rchk);
        if (s23) stage_g(Ag + t3k, lda, S4, r0, srow, schk);
        BAR8; mma16<0>(af, bfv, acc); BAR8;

        // ph8: (ks1,ih1); stage B-ks1(t3) -> S7; vmcnt
        rd4(af, S5, abase + 64, fr, rchk);
        if (s23) {
            stage_g(Bg + t3k + 32, ldb, S7, r0, srow, schk);
            asm volatile("s_waitcnt vmcnt(6)" ::: "memory");
        } else {
            asm volatile("s_waitcnt vmcnt(0)" ::: "memory");
        }
        BAR8; mma16<1>(af, bfv, acc); BAR8;
    }
}

// ---------------------------------------------------------------------------
// 8-phase kernels (main path). Fragment map (verified): C row = m0 +
// wm2*128 + ig*16 + fq*4 + t, col = n0 + wn4*64 + j*16 + fr.
// ---------------------------------------------------------------------------
__global__ __launch_bounds__(512, 2) void gemm_qkv_all8(
    const bf16_t* __restrict__ h_all, const bf16_t* __restrict__ Wb,
    const float* __restrict__ bq, const float* __restrict__ bk,
    const float* __restrict__ bv,
    bf16_t* __restrict__ q_all, bf16_t* __restrict__ k_all,
    bf16_t* __restrict__ v_all)
{
    __shared__ bf16_t lds8[8 * SL8];
    const int sel = blockIdx.z >> 3;
    const int b   = blockIdx.z & 7;
    const bf16_t* A = h_all + (size_t)b * NCb;
    const bf16_t* B = Wb + (size_t)sel * WSZ;
    const float* bias = (sel == 0) ? bq : (sel == 1) ? bk : bv;
    bf16_t* out = ((sel == 0) ? q_all : (sel == 1) ? k_all : v_all)
                + (size_t)b * NCb;
    const size_t m0 = (size_t)blockIdx.x * 256, n0 = (size_t)blockIdx.y * 256;

    f4v acc[8][4];
#pragma unroll
    for (int i = 0; i < 8; i++)
#pragma unroll
        for (int j = 0; j < 4; j++) acc[i][j] = (f4v){0.f, 0.f, 0.f, 0.f};

    gemm_core8(A, B, 512, 512, 512, m0, n0, lds8, acc);

    const int lane = threadIdx.x & 63, wave = threadIdx.x >> 6;
    const int wm2 = wave >> 2, wn4 = wave & 3;
    const int fr = lane & 15, fq = lane >> 4;

    if (sel < 2) {
#pragma unroll
        for (int ig = 0; ig < 8; ig++) {
            const int mb = (int)m0 + wm2 * 128 + ig * 16 + fq * 4;
#pragma unroll
            for (int j = 0; j < 4; j++) {
                const int n = (int)n0 + wn4 * 64 + j * 16 + fr;
                const float bn = bias[n];
#pragma unroll
                for (int t = 0; t < 4; t++)
                    out[(size_t)(mb + t) * 512 + n] =
                        (bf16_t)(acc[ig][j][t] + bn);
            }
        }
    } else {
#pragma unroll
        for (int ig = 0; ig < 8; ig++) {
            const int mb = (int)m0 + wm2 * 128 + ig * 16 + fq * 4;
#pragma unroll
            for (int j = 0; j < 4; j++) {
                const int n = (int)n0 + wn4 * 64 + j * 16 + fr;
                const float bn = bias[n];
                bf4v pk;
#pragma unroll
                for (int t = 0; t < 4; t++)
                    pk[t] = (bf16_t)(acc[ig][j][t] + bn);
                *(bf4v*)(out + (size_t)n * NN + mb) = pk;
            }
        }
    }
}

__global__ __launch_bounds__(512, 2) void gemm_qkt8(
    const bf16_t* __restrict__ q_all, const bf16_t* __restrict__ k_all,
    bf16_t* __restrict__ S2b, int bp, float scale)
{
    __shared__ bf16_t lds8[8 * SL8];
    const int z = blockIdx.z;
    const bf16_t* A = q_all + (size_t)(bp + z) * NCb;
    const bf16_t* B = k_all + (size_t)(bp + z) * NCb;
    bf16_t* out = S2b + (size_t)z * NN * NN;
    const size_t m0 = (size_t)blockIdx.x * 256, n0 = (size_t)blockIdx.y * 256;

    f4v acc[8][4];
#pragma unroll
    for (int i = 0; i < 8; i++)
#pragma unroll
        for (int j = 0; j < 4; j++) acc[i][j] = (f4v){0.f, 0.f, 0.f, 0.f};

    gemm_core8(A, B, 512, 512, 512, m0, n0, lds8, acc);

    const int lane = threadIdx.x & 63, wave = threadIdx.x >> 6;
    const int wm2 = wave >> 2, wn4 = wave & 3;
    const int fr = lane & 15, fq = lane >> 4;
#pragma unroll
    for (int ig = 0; ig < 8; ig++) {
        const int mb = (int)m0 + wm2 * 128 + ig * 16 + fq * 4;
#pragma unroll
        for (int j = 0; j < 4; j++) {
            const int n = (int)n0 + wn4 * 64 + j * 16 + fr;
#pragma unroll
            for (int t = 0; t < 4; t++)
                out[(size_t)(mb + t) * NN + n] = (bf16_t)(acc[ig][j][t] * scale);
        }
    }
}

__global__ __launch_bounds__(512, 2) void gemm_pv28(
    const bf16_t* __restrict__ S2b, const bf16_t* __restrict__ v_all,
    float* __restrict__ P, int bp)
{
    __shared__ bf16_t lds8[8 * SL8];
    const int slot = blockIdx.z >> 2;
    const int s    = blockIdx.z & 3;
    const int k0   = s * 1024;
    const bf16_t* A = S2b + (size_t)slot * NN * NN + k0;
    const bf16_t* B = v_all + (size_t)(bp + slot) * NCb + k0;
    float* out = P + ((size_t)slot * 4 + s) * NCb;
    const size_t m0 = (size_t)blockIdx.x * 256, n0 = (size_t)blockIdx.y * 256;

    f4v acc[8][4];
#pragma unroll
    for (int i = 0; i < 8; i++)
#pragma unroll
        for (int j = 0; j < 4; j++) acc[i][j] = (f4v){0.f, 0.f, 0.f, 0.f};

    gemm_core8(A, B, 1024, NN, NN, m0, n0, lds8, acc);

    const int lane = threadIdx.x & 63, wave = threadIdx.x >> 6;
    const int wm2 = wave >> 2, wn4 = wave & 3;
    const int fr = lane & 15, fq = lane >> 4;
#pragma unroll
    for (int ig = 0; ig < 8; ig++) {
        const int mb = (int)m0 + wm2 * 128 + ig * 16 + fq * 4;
#pragma unroll
        for (int j = 0; j < 4; j++) {
            const int n = (int)n0 + wn4 * 64 + j * 16 + fr;
#pragma unroll
            for (int t = 0; t < 4; t++)
                out[(size_t)(mb + t) * CC + n] = acc[ig][j][t];
        }
    }
}

__global__ __launch_bounds__(512, 2) void gemm_out_all8(
    const bf16_t* __restrict__ Oall, const bf16_t* __restrict__ Wo,
    float* __restrict__ outg, const float* __restrict__ bo,
    const float* __restrict__ x)
{
    __shared__ bf16_t lds8[8 * SL8];
    const int b = blockIdx.z;
    const bf16_t* A = Oall + (size_t)b * NCb;
    float* out = outg + (size_t)b * CC * NN;
    const float* resid = x + (size_t)b * CC * NN;
    const size_t m0 = (size_t)blockIdx.x * 256, n0 = (size_t)blockIdx.y * 256;

    f4v acc[8][4];
#pragma unroll
    for (int i = 0; i < 8; i++)
#pragma unroll
        for (int j = 0; j < 4; j++) acc[i][j] = (f4v){0.f, 0.f, 0.f, 0.f};

    gemm_core8(A, Wo, 512, 512, 512, m0, n0, lds8, acc);

    const int lane = threadIdx.x & 63, wave = threadIdx.x >> 6;
    const int wm2 = wave >> 2, wn4 = wave & 3;
    const int fr = lane & 15, fq = lane >> 4;
#pragma unroll
    for (int ig = 0; ig < 8; ig++) {
        const int mb = (int)m0 + wm2 * 128 + ig * 16 + fq * 4;
#pragma unroll
        for (int j = 0; j < 4; j++) {
            const int n = (int)n0 + wn4 * 64 + j * 16 + fr;
            const float bn = bo[n];
            float4 rq = *(const float4*)(resid + (size_t)n * NN + mb);
            float4 o4;
            o4.x = acc[ig][j][0] + bn + rq.x;
            o4.y = acc[ig][j][1] + bn + rq.y;
            o4.z = acc[ig][j][2] + bn + rq.z;
            o4.w = acc[ig][j][3] + bn + rq.w;
            *(float4*)(out + (size_t)n * NN + mb) = o4;
        }
    }
}

// ---------------------------------------------------------------------------
// Reduce 4 fp32 partials -> bf16 O for a PAIR of batches. grid (NCb/1024, 2).
// ---------------------------------------------------------------------------
__global__ __launch_bounds__(256) void pv_reduce2(const float* __restrict__ P,
                                                  bf16_t* __restrict__ O_all,
                                                  int bp)
{
    const int slot = blockIdx.y;
    const size_t i = ((size_t)blockIdx.x * 256 + threadIdx.x) * 4;
    const float* Ps = P + (size_t)slot * 4 * NCb;
    float4 sv = *(const float4*)(Ps + i);
#pragma unroll
    for (int z = 1; z < 4; z++) {
        float4 t = *(const float4*)(Ps + (size_t)z * NCb + i);
        sv.x += t.x; sv.y += t.y; sv.z += t.z; sv.w += t.w;
    }
    bf4v o;
    o[0] = (bf16_t)sv.x; o[1] = (bf16_t)sv.y;
    o[2] = (bf16_t)sv.z; o[3] = (bf16_t)sv.w;
    *(bf4v*)(O_all + (size_t)(bp + slot) * NCb + i) = o;
}

// ---------------------------------------------------------------------------
// Row softmax over S (rows x 4096 bf16), in place. 1 wave per row.
// ---------------------------------------------------------------------------
__global__ __launch_bounds__(256) void softmax_kernel(bf16_t* __restrict__ S)
{
    const int wave = threadIdx.x >> 6, lane = threadIdx.x & 63;
    const size_t row = (size_t)blockIdx.x * 4 + wave;
    bf16_t* p = S + row * NN;
    float f[64];
    float mx = -1e30f;
#pragma unroll
    for (int c = 0; c < 8; c++) {
        bf8v v = ((const bf8v*)p)[c * 64 + lane];
#pragma unroll
        for (int j = 0; j < 8; j++) {
            f[c * 8 + j] = (float)v[j];
            mx = fmaxf(mx, f[c * 8 + j]);
        }
    }
#pragma unroll
    for (int off = 32; off > 0; off >>= 1) mx = fmaxf(mx, __shfl_xor(mx, off));
    float sum = 0.f;
#pragma unroll
    for (int i = 0; i < 64; i++) { f[i] = expf(f[i] - mx); sum += f[i]; }
#pragma unroll
    for (int off = 32; off > 0; off >>= 1) sum += __shfl_xor(sum, off);
    const float inv = 1.f / sum;
#pragma unroll
    for (int c = 0; c < 8; c++) {
        bf8v o;
#pragma unroll
        for (int j = 0; j < 8; j++) o[j] = (bf16_t)(f[c * 8 + j] * inv);
        ((bf8v*)p)[c * 64 + lane] = o;
    }
}

// ---------------------------------------------------------------------------
extern "C" void kernel_launch(void* const* d_in, const int* in_sizes, int n_in,
                              void* d_out, int out_size, void* d_ws, size_t ws_size,
                              hipStream_t stream)
{
    const float* x  = (const float*)d_in[0];
    const float* gw = (const float*)d_in[1];
    const float* gb = (const float*)d_in[2];
    const float* Wq = (const float*)d_in[3];
    const float* bq = (const float*)d_in[4];
    const float* Wk = (const float*)d_in[5];
    const float* bk = (const float*)d_in[6];
    const float* Wv = (const float*)d_in[7];
    const float* bv = (const float*)d_in[8];
    const float* Wo = (const float*)d_in[9];
    const float* bo = (const float*)d_in[10];
    float* out = (float*)d_out;          // *** fp32 output ***

    bool ok = (n_in == 11) && (out_size == BB * CC * NN) &&
              (in_sizes[0] == BB * CC * NN) &&
              (in_sizes[1] == CC) && (in_sizes[2] == CC) &&
              (in_sizes[3] == WSZ) && (in_sizes[4] == CC) &&
              (in_sizes[5] == WSZ) && (in_sizes[6] == CC) &&
              (in_sizes[7] == WSZ) && (in_sizes[8] == CC) &&
              (in_sizes[9] == WSZ) && (in_sizes[10] == CC);
    if (!ok) { diag_out<<<dim3(1), 64, 0, stream>>>(out, FLG_SIZES); return; }

    const float sc = 0.044194173824159216f;           // 512^-0.5

    // ---- common small buffers ----
    bf16_t* Wb    = (bf16_t*)d_ws;                     // 4*WSZ bf16 (2 MB)
    float*  stats = (float*)(Wb + (size_t)4 * WSZ);    // 1024 floats
    double* part  = (double*)(stats + 1024);           // 2048 doubles
    bf16_t* base  = (bf16_t*)(part + 2048);
    const size_t head = (size_t)4 * WSZ * 2 + 1024 * 4 + 2048 * 8;

    const size_t sfull = (size_t)NN * NN * 2;

    cvt_w<<<dim3(256), 256, 0, stream>>>(Wq, Wk, Wv, Wo, Wb);
    gn_stats_part<<<dim3(1024), 256, 0, stream>>>(x, part);
    gn_stats_fin<<<dim3(1), 256, 0, stream>>>(part, stats);

    // ---- fully-batched pair-wise path: needs 194 MiB ws; P lives in d_out ----
    if (ws_size >= head + (size_t)4 * BB * NCb * 2 + 2 * sfull) {
        bf16_t* h_all = base;                          // (B,N,C)
        bf16_t* q_all = h_all + (size_t)BB * NCb;
        bf16_t* k_all = q_all + (size_t)BB * NCb;
        bf16_t* v_all = k_all + (size_t)BB * NCb;      // (B,C,N)
        bf16_t* S2    = v_all + (size_t)BB * NCb;      // 2 batches of S
        float*  P     = out;                           // d_out as scratch (64 MiB)
        bf16_t* O_all = h_all;                         // overlay: h dead post-qkv

        gn_apply_all<<<dim3(512, 8), 256, 0, stream>>>(x, gw, gb, stats, h_all);
        gemm_qkv_all8<<<dim3(16, 2, 24), 512, 0, stream>>>(
            h_all, Wb, bq, bk, bv, q_all, k_all, v_all);

        for (int bp = 0; bp < BB; bp += 2) {
            gemm_qkt8<<<dim3(16, 16, 2), 512, 0, stream>>>(
                q_all, k_all, S2, bp, sc);
            softmax_kernel<<<dim3(2 * NN / 4), 256, 0, stream>>>(S2);
            gemm_pv28<<<dim3(16, 2, 8), 512, 0, stream>>>(S2, v_all, P, bp);
            pv_reduce2<<<dim3(NCb / 1024, 2), 256, 0, stream>>>(P, O_all, bp);
        }

        gemm_out_all8<<<dim3(16, 2, 8), 512, 0, stream>>>(
            O_all, Wb + (size_t)3 * WSZ, out, bo, x);
        return;
    }

    // ---- fallback: per-batch path (small workspace), old 4-wave kernels ----
    bf16_t* h = base;                                  // per-batch (N,C)
    bf16_t* q = h + (size_t)NCb;
    bf16_t* k = q + (size_t)NCb;
    bf16_t* v = k + (size_t)NCb;                       // (C,N)
    bf16_t* S = v + (size_t)NCb;
    bf16_t* O = h;
    const size_t fixed = head + (size_t)4 * NCb * 2;

    if (ws_size < fixed + (size_t)128 * NN * 2) {
        diag_out<<<dim3(1), 64, 0, stream>>>(out, FLG_WS); return;
    }

    int NS = 0;
    if (ws_size >= fixed + sfull + (size_t)8 * NCb * 4)      NS = 8;
    else if (ws_size >= fixed + sfull + (size_t)4 * NCb * 4) NS = 4;
    else if (ws_size >= fixed + sfull + (size_t)2 * NCb * 4) NS = 2;

    if (NS) {
        float* P = (float*)(S + (size_t)NN * NN);
        for (int b = 0; b < BB; b++) {
            const float* xb   = x   + (size_t)b * CC * NN;
            float*       outb = out + (size_t)b * CC * NN;

            gn_apply<<<dim3(512), 256, 0, stream>>>(xb, gw, gb, stats, h, b * 32);
            gemm_qkv<<<dim3(32, 2, 3), 256, 0, stream>>>(h, Wb, bq, bk, bv, q, k, v);

            gemm_bt<0><<<dim3(32, 16), 256, 0, stream>>>(
                q, k, S, nullptr, nullptr, sc, 512, 512, 512, 4096);
            softmax_kernel<<<dim3(NN / 4), 256, 0, stream>>>(S);

            gemm_pv_split<<<dim3(32, 2, NS), 256, 0, stream>>>(S, v, P, NN / NS);
            pv_reduce<<<dim3(NCb / 1024), 256, 0, stream>>>(P, O, NS);

            gemm_bt<2><<<dim3(32, 2), 256, 0, stream>>>(
                O, Wb + (size_t)3 * WSZ, outb, bo, xb, 1.f,
                512, 512, 512, 4096);
        }
        return;
    }

    int CH = 128;
    while (CH < NN && fixed + (size_t)(CH * 2) * NN * 2 <= ws_size) CH *= 2;

    for (int b = 0; b < BB; b++) {
        const float* xb   = x   + (size_t)b * CC * NN;
        float*       outb = out + (size_t)b * CC * NN;

        gn_apply<<<dim3(512), 256, 0, stream>>>(xb, gw, gb, stats, h, b * 32);
        gemm_qkv<<<dim3(32, 2, 3), 256, 0, stream>>>(h, Wb, bq, bk, bv, q, k, v);

        for (int r0 = 0; r0 < NN; r0 += CH) {
            gemm_bt<0><<<dim3(CH / 128, 16), 256, 0, stream>>>(
                q + (size_t)r0 * CC, k, S, nullptr, nullptr, sc,
                512, 512, 512, 4096);
            softmax_kernel<<<dim3(CH / 4), 256, 0, stream>>>(S);
            gemm_bt<0><<<dim3(CH / 128, 2), 256, 0, stream>>>(
                S, v, O + (size_t)r0 * CC, nullptr, nullptr, 1.f,
                4096, 4096, 4096, 512);
        }

        gemm_bt<2><<<dim3(32, 2), 256, 0, stream>>>(
            O, Wb + (size_t)3 * WSZ, outb, bo, xb, 1.f,
            512, 512, 512, 4096);
    }
}

// Round 10
// 728.497 us; speedup vs baseline: 1.0391x; 1.0391x over previous
//
#include <hip/hip_runtime.h>
#include <math.h>

typedef __bf16 bf16_t;
typedef __bf16 bf8v __attribute__((ext_vector_type(8)));
typedef __bf16 bf4v __attribute__((ext_vector_type(4)));
typedef float  f4v  __attribute__((ext_vector_type(4)));

#define BB  8
#define CC  512
#define NN  4096
#define CPG 16
#define NCb (NN * CC)
#define WSZ (CC * CC)

#define FLG_SIZES 805306368.f
#define FLG_WS    536870912.f

__global__ void diag_out(float* out, float v) { if (threadIdx.x == 0) out[0] = v; }

// async global->LDS, 16B per lane; LDS dest is wave-uniform base + lane*16.
__device__ __forceinline__ void gload_lds16(const bf16_t* g, bf16_t* l)
{
    __builtin_amdgcn_global_load_lds(
        (const __attribute__((address_space(1))) unsigned int*)g,
        (__attribute__((address_space(3))) unsigned int*)l, 16, 0, 0);
}

// ---------------------------------------------------------------------------
// Convert the four 512x512 fp32 weights to bf16, packed [Wq|Wk|Wv|Wo].
// ---------------------------------------------------------------------------
__global__ __launch_bounds__(256) void cvt_w(const float* __restrict__ a,
                                             const float* __restrict__ b,
                                             const float* __restrict__ c,
                                             const float* __restrict__ d,
                                             bf16_t* __restrict__ o)
{
    const int i = (blockIdx.x * 256 + threadIdx.x) * 4;
    const float* srcs[4] = {a, b, c, d};
#pragma unroll
    for (int m = 0; m < 4; m++) {
        float4 v = *(const float4*)(srcs[m] + i);
        bf4v w;
        w[0] = (bf16_t)v.x; w[1] = (bf16_t)v.y;
        w[2] = (bf16_t)v.z; w[3] = (bf16_t)v.w;
        *(bf4v*)(o + (size_t)m * WSZ + i) = w;
    }
}

// ---------------------------------------------------------------------------
// GroupNorm stats, two-stage (1024 partial blocks + 1 finish block).
// ---------------------------------------------------------------------------
__global__ __launch_bounds__(256) void gn_stats_part(const float* __restrict__ x,
                                                     double* __restrict__ part)
{
    const int bg = blockIdx.x >> 2;
    const int sl = blockIdx.x & 3;
    const int tid = threadIdx.x;
    const float4* xv = (const float4*)(x + (size_t)bg * CPG * NN) + sl * 4096;
    double s[4] = {0, 0, 0, 0}, ss[4] = {0, 0, 0, 0};
#pragma unroll
    for (int ii = 0; ii < 16; ii++) {
        float4 v = xv[tid + ii * 256];
        const int a = ii & 3;
        s[a]  += (double)v.x + (double)v.y + (double)v.z + (double)v.w;
        ss[a] += (double)v.x * v.x + (double)v.y * v.y
               + (double)v.z * v.z + (double)v.w * v.w;
    }
    double sT = s[0] + s[1] + s[2] + s[3];
    double ssT = ss[0] + ss[1] + ss[2] + ss[3];
    __shared__ double l1[256], l2[256];
    l1[tid] = sT; l2[tid] = ssT;
    __syncthreads();
    for (int o = 128; o > 0; o >>= 1) {
        if (tid < o) { l1[tid] += l1[tid + o]; l2[tid] += l2[tid + o]; }
        __syncthreads();
    }
    if (tid == 0) {
        part[(size_t)blockIdx.x * 2]     = l1[0];
        part[(size_t)blockIdx.x * 2 + 1] = l2[0];
    }
}

__global__ __launch_bounds__(256) void gn_stats_fin(const double* __restrict__ part,
                                                    float* __restrict__ stats)
{
    const int bg = threadIdx.x;          // 0..255
    double s = 0.0, ss = 0.0;
#pragma unroll
    for (int sl = 0; sl < 4; sl++) {
        s  += part[(size_t)(bg * 4 + sl) * 2];
        ss += part[(size_t)(bg * 4 + sl) * 2 + 1];
    }
    double mean = s * (1.0 / 65536.0);
    double var  = ss * (1.0 / 65536.0) - mean * mean;
    stats[bg * 2]     = (float)mean;
    stats[bg * 2 + 1] = (float)(1.0 / sqrt(var + 1e-6));
}

// ---------------------------------------------------------------------------
// GN apply, ALL batches: x (B,C,N) fp32 -> h_all (B,N,C) bf16. grid (512, 8).
// ---------------------------------------------------------------------------
__global__ __launch_bounds__(256) void gn_apply_all(const float* __restrict__ x,
                                                    const float* __restrict__ gw,
                                                    const float* __restrict__ gb,
                                                    const float* __restrict__ stats,
                                                    bf16_t* __restrict__ h_all)
{
    const int b  = blockIdx.y;
    const int g  = blockIdx.x >> 4;
    const int sl = blockIdx.x & 15;
    const float* xp = x + (size_t)b * CC * NN + (size_t)g * CPG * NN;
    bf16_t* h = h_all + (size_t)b * NCb;
    const int tid = threadIdx.x;
    const float mean = stats[(b * 32 + g) * 2];
    const float rstd = stats[(b * 32 + g) * 2 + 1];
    const int cw = tid & 15;
    const float aa = rstd * gw[g * CPG + cw];
    const float bb = gb[g * CPG + cw] - mean * aa;

    __shared__ float tile[CPG][260];
    const int n0 = sl * 256;
    for (int i = tid; i < (CPG * 256) / 4; i += 256) {
        int c  = i >> 6;
        int n4 = i & 63;
        float4 v = *(const float4*)(xp + (size_t)c * NN + n0 + n4 * 4);
        tile[c][n4 * 4 + 0] = v.x;
        tile[c][n4 * 4 + 1] = v.y;
        tile[c][n4 * 4 + 2] = v.z;
        tile[c][n4 * 4 + 3] = v.w;
    }
    __syncthreads();
#pragma unroll
    for (int j = 0; j < 16; j++) {
        int n = (tid >> 4) + 16 * j;
        float v = tile[cw][n] * aa + bb;
        h[(size_t)(n0 + n) * CC + g * CPG + cw] = (bf16_t)v;
    }
}

// ---------------------------------------------------------------------------
// GN apply for one batch (fallback path).
// ---------------------------------------------------------------------------
__global__ __launch_bounds__(256) void gn_apply(const float* __restrict__ xb,
                                                const float* __restrict__ gw,
                                                const float* __restrict__ gb,
                                                const float* __restrict__ stats,
                                                bf16_t* __restrict__ h,
                                                int bg0)
{
    const int g  = blockIdx.x >> 4;
    const int sl = blockIdx.x & 15;
    const float* xp = xb + (size_t)g * CPG * NN;
    const int tid = threadIdx.x;
    const float mean = stats[(bg0 + g) * 2];
    const float rstd = stats[(bg0 + g) * 2 + 1];
    const int cw = tid & 15;
    const float aa = rstd * gw[g * CPG + cw];
    const float bb = gb[g * CPG + cw] - mean * aa;

    __shared__ float tile[CPG][260];
    const int n0 = sl * 256;
    for (int i = tid; i < (CPG * 256) / 4; i += 256) {
        int c  = i >> 6;
        int n4 = i & 63;
        float4 v = *(const float4*)(xp + (size_t)c * NN + n0 + n4 * 4);
        tile[c][n4 * 4 + 0] = v.x;
        tile[c][n4 * 4 + 1] = v.y;
        tile[c][n4 * 4 + 2] = v.z;
        tile[c][n4 * 4 + 3] = v.w;
    }
    __syncthreads();
#pragma unroll
    for (int j = 0; j < 16; j++) {
        int n = (tid >> 4) + 16 * j;
        float v = tile[cw][n] * aa + bb;
        h[(size_t)(n0 + n) * CC + g * CPG + cw] = (bf16_t)v;
    }
}

// ===========================================================================
// OLD 4-wave 128x256 core (fallback path only).
// ===========================================================================
#define ABUF (128 * 32)
#define BBUF (256 * 32)
#define NBUF 3

__device__ __forceinline__ void stage_tile(
    const bf16_t* pa, const bf16_t* pb, int lda, int ldb,
    bf16_t* lA, bf16_t* lB)
{
    gload_lds16(pa,                     lA);
    gload_lds16(pa + (size_t)16 * lda,  lA + 16 * 32);
    gload_lds16(pb,                     lB);
    gload_lds16(pb + (size_t)16 * ldb,  lB + 16 * 32);
    gload_lds16(pb + (size_t)32 * ldb,  lB + 32 * 32);
    gload_lds16(pb + (size_t)48 * ldb,  lB + 48 * 32);
}

__device__ __forceinline__ void gemm_core_w(
    const bf16_t* __restrict__ A, const bf16_t* __restrict__ B,
    int K, int lda, int ldb, size_t m0, size_t n0,
    bf16_t* Asm, bf16_t* Bsm,
    int wave, int lane, int wm, int wn, int fr, int fq, f4v acc[4][8])
{
    const int gr  = lane >> 2;
    const int gcs = (((lane & 3) ^ (gr & 3)) << 3);
    const bf16_t* pa = A + (m0 + wave * 32 + gr) * lda + gcs;
    const bf16_t* pb = B + (n0 + wave * 64 + gr) * ldb + gcs;
    const int la0 = (wave * 32) * 32;
    const int lb0 = (wave * 64) * 32;
    const int fqs = ((fq ^ (fr & 3)) << 3);

    stage_tile(pa, pb, lda, ldb, Asm + la0, Bsm + lb0);
    if (K > 32)
        stage_tile(pa + 32, pb + 32, lda, ldb,
                   Asm + ABUF + la0, Bsm + BBUF + lb0);

    int buf = 0;
    for (int kt = 0; kt < K; kt += 32) {
        if (kt + 64 < K) {
            const int nb = (buf + 2 >= NBUF) ? buf + 2 - NBUF : buf + 2;
            stage_tile(pa + kt + 64, pb + kt + 64, lda, ldb,
                       Asm + nb * ABUF + la0, Bsm + nb * BBUF + lb0);
            asm volatile("s_waitcnt vmcnt(12)" ::: "memory");
        } else if (kt + 32 < K) {
            asm volatile("s_waitcnt vmcnt(6)" ::: "memory");
        } else {
            asm volatile("s_waitcnt vmcnt(0)" ::: "memory");
        }
        __builtin_amdgcn_s_barrier();

        const bf16_t* As = Asm + buf * ABUF;
        const bf16_t* Bs = Bsm + buf * BBUF;
        bf8v af[4], bfv[8];
#pragma unroll
        for (int j = 0; j < 8; j++)
            bfv[j] = *(const bf8v*)(Bs + (wn + j * 16 + fr) * 32 + fqs);
#pragma unroll
        for (int i = 0; i < 4; i++)
            af[i] = *(const bf8v*)(As + (wm + i * 16 + fr) * 32 + fqs);
#pragma unroll
        for (int i = 0; i < 4; i++)
#pragma unroll
            for (int j = 0; j < 8; j++)
                acc[i][j] = __builtin_amdgcn_mfma_f32_16x16x32_bf16(
                    af[i], bfv[j], acc[i][j], 0, 0, 0);

        __builtin_amdgcn_s_barrier();
        buf = (buf + 1 == NBUF) ? 0 : buf + 1;
    }
}

// old-style kernels kept for the small-workspace fallback path
template <int MODE>
__global__ __launch_bounds__(256, 2) void gemm_bt(
    const bf16_t* __restrict__ A, const bf16_t* __restrict__ B,
    void* __restrict__ Og, const float* __restrict__ bias,
    const float* __restrict__ resid, float scale,
    int K, int lda, int ldb, int ldo)
{
    __shared__ bf16_t Asm[NBUF * ABUF];
    __shared__ bf16_t Bsm[NBUF * BBUF];
    const int tid  = threadIdx.x;
    const int lane = tid & 63, wave = tid >> 6;
    const int wm = (wave >> 1) << 6, wn = (wave & 1) << 7;
    const int fr = lane & 15, fq = lane >> 4;
    const size_t m0 = (size_t)blockIdx.x * 128, n0 = (size_t)blockIdx.y * 256;

    f4v acc[4][8];
#pragma unroll
    for (int i = 0; i < 4; i++)
#pragma unroll
        for (int j = 0; j < 8; j++) acc[i][j] = (f4v){0.f, 0.f, 0.f, 0.f};

    gemm_core_w(A, B, K, lda, ldb, m0, n0, Asm, Bsm,
                wave, lane, wm, wn, fr, fq, acc);

    if (MODE == 0) {
        bf16_t* out = (bf16_t*)Og;
#pragma unroll
        for (int i = 0; i < 4; i++) {
            const int mb = (int)m0 + wm + i * 16 + fq * 4;
#pragma unroll
            for (int j = 0; j < 8; j++) {
                const int n = (int)n0 + wn + j * 16 + fr;
                const float bn = bias ? bias[n] : 0.f;
#pragma unroll
                for (int t = 0; t < 4; t++)
                    out[(size_t)(mb + t) * ldo + n] =
                        (bf16_t)(acc[i][j][t] * scale + bn);
            }
        }
    } else {
        float* out = (float*)Og;
#pragma unroll
        for (int i = 0; i < 4; i++) {
            const int mb = (int)m0 + wm + i * 16 + fq * 4;
#pragma unroll
            for (int j = 0; j < 8; j++) {
                const int n = (int)n0 + wn + j * 16 + fr;
                const float bn = bias[n];
                float4 rq = *(const float4*)(resid + (size_t)n * ldo + mb);
                float4 o4;
                o4.x = acc[i][j][0] * scale + bn + rq.x;
                o4.y = acc[i][j][1] * scale + bn + rq.y;
                o4.z = acc[i][j][2] * scale + bn + rq.z;
                o4.w = acc[i][j][3] * scale + bn + rq.w;
                *(float4*)(out + (size_t)n * ldo + mb) = o4;
            }
        }
    }
}

__global__ __launch_bounds__(256, 2) void gemm_qkv(
    const bf16_t* __restrict__ h, const bf16_t* __restrict__ Wb,
    const float* __restrict__ bq, const float* __restrict__ bk,
    const float* __restrict__ bv,
    bf16_t* __restrict__ q, bf16_t* __restrict__ k, bf16_t* __restrict__ v)
{
    __shared__ bf16_t Asm[NBUF * ABUF];
    __shared__ bf16_t Bsm[NBUF * BBUF];
    const int z = blockIdx.z;
    const bf16_t* B = Wb + (size_t)z * WSZ;
    const float* bias = (z == 0) ? bq : (z == 1) ? bk : bv;
    bf16_t* out = (z == 0) ? q : (z == 1) ? k : v;

    const int tid  = threadIdx.x;
    const int lane = tid & 63, wave = tid >> 6;
    const int wm = (wave >> 1) << 6, wn = (wave & 1) << 7;
    const int fr = lane & 15, fq = lane >> 4;
    const size_t m0 = (size_t)blockIdx.x * 128, n0 = (size_t)blockIdx.y * 256;

    f4v acc[4][8];
#pragma unroll
    for (int i = 0; i < 4; i++)
#pragma unroll
        for (int j = 0; j < 8; j++) acc[i][j] = (f4v){0.f, 0.f, 0.f, 0.f};

    gemm_core_w(h, B, 512, 512, 512, m0, n0, Asm, Bsm,
                wave, lane, wm, wn, fr, fq, acc);

    if (z < 2) {
#pragma unroll
        for (int i = 0; i < 4; i++) {
            const int mb = (int)m0 + wm + i * 16 + fq * 4;
#pragma unroll
            for (int j = 0; j < 8; j++) {
                const int n = (int)n0 + wn + j * 16 + fr;
                const float bn = bias[n];
#pragma unroll
                for (int t = 0; t < 4; t++)
                    out[(size_t)(mb + t) * 512 + n] =
                        (bf16_t)(acc[i][j][t] + bn);
            }
        }
    } else {
#pragma unroll
        for (int i = 0; i < 4; i++) {
            const int mb = (int)m0 + wm + i * 16 + fq * 4;
#pragma unroll
            for (int j = 0; j < 8; j++) {
                const int n = (int)n0 + wn + j * 16 + fr;
                const float bn = bias[n];
                bf4v pk;
#pragma unroll
                for (int t = 0; t < 4; t++)
                    pk[t] = (bf16_t)(acc[i][j][t] + bn);
                *(bf4v*)(out + (size_t)n * NN + mb) = pk;
            }
        }
    }
}

__global__ __launch_bounds__(256, 2) void gemm_pv_split(
    const bf16_t* __restrict__ A, const bf16_t* __restrict__ B,
    float* __restrict__ P, int KS)
{
    __shared__ bf16_t Asm[NBUF * ABUF];
    __shared__ bf16_t Bsm[NBUF * BBUF];
    const int tid  = threadIdx.x;
    const int lane = tid & 63, wave = tid >> 6;
    const int wm = (wave >> 1) << 6, wn = (wave & 1) << 7;
    const int fr = lane & 15, fq = lane >> 4;
    const size_t m0 = (size_t)blockIdx.x * 128, n0 = (size_t)blockIdx.y * 256;
    const int z  = blockIdx.z;
    const int k0 = z * KS;

    f4v acc[4][8];
#pragma unroll
    for (int i = 0; i < 4; i++)
#pragma unroll
        for (int j = 0; j < 8; j++) acc[i][j] = (f4v){0.f, 0.f, 0.f, 0.f};

    gemm_core_w(A + k0, B + k0, KS, NN, NN, m0, n0, Asm, Bsm,
                wave, lane, wm, wn, fr, fq, acc);

    float* out = P + (size_t)z * NCb;
#pragma unroll
    for (int i = 0; i < 4; i++) {
        const int mb = (int)m0 + wm + i * 16 + fq * 4;
#pragma unroll
        for (int j = 0; j < 8; j++) {
            const int n = (int)n0 + wn + j * 16 + fr;
#pragma unroll
            for (int t = 0; t < 4; t++)
                out[(size_t)(mb + t) * CC + n] = acc[i][j][t];
        }
    }
}

__global__ __launch_bounds__(256) void pv_reduce(const float* __restrict__ P,
                                                 bf16_t* __restrict__ O, int NS)
{
    const size_t i = ((size_t)blockIdx.x * 256 + threadIdx.x) * 4;
    float4 s = *(const float4*)(P + i);
    for (int z = 1; z < NS; z++) {
        float4 t = *(const float4*)(P + (size_t)z * NCb + i);
        s.x += t.x; s.y += t.y; s.z += t.z; s.w += t.w;
    }
    bf4v o;
    o[0] = (bf16_t)s.x; o[1] = (bf16_t)s.y;
    o[2] = (bf16_t)s.z; o[3] = (bf16_t)s.w;
    *(bf4v*)(O + i) = o;
}

// ===========================================================================
// 256x256 8-wave 8-phase GEMM core (m201 template, plain HIP).
// Conflict-free swizzle (round 9, verified: SQ_LDS_BANK_CONFLICT -> 0):
// logical chunk c of row r stored at c^((r>>1)&3), applied BOTH sides
// (pre-swizzled global source + swizzled read offset; rule #21).
// ===========================================================================
#define SL8 8192   // bf16 elems per slot (256 x 32)

__device__ __forceinline__ void stage_g(const bf16_t* g, int ld, bf16_t* slot,
                                        int r0, int srow, int schk)
{
    gload_lds16(g + (size_t)(r0 + srow) * ld + schk,      slot + r0 * 32);
    gload_lds16(g + (size_t)(r0 + 16 + srow) * ld + schk, slot + (r0 + 16) * 32);
}

__device__ __forceinline__ void rd4(bf8v* dst, const bf16_t* slot, int base,
                                    int fr, int rchk)
{
#pragma unroll
    for (int i = 0; i < 4; i++)
        dst[i] = *(const bf8v*)(slot + (base + i * 16 + fr) * 32 + rchk);
}

template <int IH>
__device__ __forceinline__ void mma16(const bf8v* af, const bf8v* bfv,
                                      f4v (&acc)[8][4])
{
    __builtin_amdgcn_s_setprio(1);
#pragma unroll
    for (int i = 0; i < 4; i++)
#pragma unroll
        for (int j = 0; j < 4; j++)
            acc[IH * 4 + i][j] = __builtin_amdgcn_mfma_f32_16x16x32_bf16(
                af[i], bfv[j], acc[IH * 4 + i][j], 0, 0, 0);
    __builtin_amdgcn_s_setprio(0);
}

#define FENCE8 asm volatile("" ::: "memory")
#define BAR8   do { FENCE8; __builtin_amdgcn_s_barrier(); FENCE8; } while (0)

__device__ __forceinline__ void gemm_core8(
    const bf16_t* __restrict__ A, const bf16_t* __restrict__ B,
    int K, int lda, int ldb, size_t m0, size_t n0,
    bf16_t* lds, f4v (&acc)[8][4])
{
    const int tid  = threadIdx.x;
    const int lane = tid & 63, wave = tid >> 6;
    const int wm2 = wave >> 2, wn4 = wave & 3;
    const int fr = lane & 15, fq = lane >> 4;
    const int srow = lane >> 2;
    const int schk = ((lane & 3) ^ ((srow >> 1) & 3)) << 3;   // elems
    const int r0   = wave * 32;
    const int rchk = ((fq ^ ((fr >> 1) & 3)) << 3);           // elems

    const bf16_t* Ag = A + m0 * lda;
    const bf16_t* Bg = B + n0 * ldb;
    const int NT = K >> 6;                             // K-tiles (>=2, even)

    bf16_t* S0 = lds;
    bf16_t* S1 = lds + 1 * SL8;
    bf16_t* S2 = lds + 2 * SL8;
    bf16_t* S3 = lds + 3 * SL8;
    bf16_t* S4 = lds + 4 * SL8;
    bf16_t* S5 = lds + 5 * SL8;
    bf16_t* S6 = lds + 6 * SL8;
    bf16_t* S7 = lds + 7 * SL8;

    const int abase = wm2 * 128;
    const int bbase = wn4 * 64;

    // prologue: T0 {Aks0,Aks1,Bks0,Bks1}, T1 {Bks0,Aks0,Bks1}  (14 loads)
    stage_g(Ag,      lda, S0, r0, srow, schk);
    stage_g(Ag + 32, lda, S1, r0, srow, schk);
    stage_g(Bg,      ldb, S2, r0, srow, schk);
    stage_g(Bg + 32, ldb, S3, r0, srow, schk);
    stage_g(Bg + 64, ldb, S6, r0, srow, schk);
    stage_g(Ag + 64, lda, S4, r0, srow, schk);
    stage_g(Bg + 96, ldb, S7, r0, srow, schk);
    asm volatile("s_waitcnt vmcnt(6)" ::: "memory");
    __builtin_amdgcn_s_barrier();
    FENCE8;

    bf8v af[4], bfv[4];
    const int iters = NT >> 1;
    for (int it = 0; it < iters; it++) {
        const int t1k = (2 * it + 1) << 6;
        const int t2k = (2 * it + 2) << 6;
        const int t3k = (2 * it + 3) << 6;
        const bool s23 = (2 * it + 2) < NT;   // NT even => t2,t3 guard equal

        // ph1: T(2it) (ks0,ih0) buf0; stage A-ks1(2it+1) -> S5
        rd4(af, S0, abase, fr, rchk);
        rd4(bfv, S2, bbase, fr, rchk);
        stage_g(Ag + t1k + 32, lda, S5, r0, srow, schk);
        BAR8; mma16<0>(af, bfv, acc); BAR8;

        // ph2: (ks0,ih1); stage B-ks0(t2) -> S2
        rd4(af, S0, abase + 64, fr, rchk);
        if (s23) stage_g(Bg + t2k, ldb, S2, r0, srow, schk);
        BAR8; mma16<1>(af, bfv, acc); BAR8;

        // ph3: (ks1,ih0); stage A-ks0(t2) -> S0
        rd4(af, S1, abase, fr, rchk);
        rd4(bfv, S3, bbase, fr, rchk);
        if (s23) stage_g(Ag + t2k, lda, S0, r0, srow, schk);
        BAR8; mma16<0>(af, bfv, acc); BAR8;

        // ph4: (ks1,ih1); stage B-ks1(t2) -> S3; vmcnt
        rd4(af, S1, abase + 64, fr, rchk);
        if (s23) {
            stage_g(Bg + t2k + 32, ldb, S3, r0, srow, schk);
            asm volatile("s_waitcnt vmcnt(6)" ::: "memory");
        } else {
            asm volatile("s_waitcnt vmcnt(0)" ::: "memory");
        }
        BAR8; mma16<1>(af, bfv, acc); BAR8;

        // ph5: T(2it+1) (ks0,ih0) buf1; stage A-ks1(t2) -> S1
        rd4(af, S4, abase, fr, rchk);
        rd4(bfv, S6, bbase, fr, rchk);
        if (s23) stage_g(Ag + t2k + 32, lda, S1, r0, srow, schk);
        BAR8; mma16<0>(af, bfv, acc); BAR8;

        // ph6: (ks0,ih1); stage B-ks0(t3) -> S6
        rd4(af, S4, abase + 64, fr, rchk);
        if (s23) stage_g(Bg + t3k, ldb, S6, r0, srow, schk);
        BAR8; mma16<1>(af, bfv, acc); BAR8;

        // ph7: (ks1,ih0); stage A-ks0(t3) -> S4
        rd4(af, S5, abase, fr, rchk);
        rd4(bfv, S7, bbase, fr, rchk);
        if (s23) stage_g(Ag + t3k, lda, S4, r0, srow, schk);
        BAR8; mma16<0>(af, bfv, acc); BAR8;

        // ph8: (ks1,ih1); stage B-ks1(t3) -> S7; vmcnt
        rd4(af, S5, abase + 64, fr, rchk);
        if (s23) {
            stage_g(Bg + t3k + 32, ldb, S7, r0, srow, schk);
            asm volatile("s_waitcnt vmcnt(6)" ::: "memory");
        } else {
            asm volatile("s_waitcnt vmcnt(0)" ::: "memory");
        }
        BAR8; mma16<1>(af, bfv, acc); BAR8;
    }
}

// ---------------------------------------------------------------------------
// 8-phase kernels (main path). Fragment map (verified): C row = m0 +
// wm2*128 + ig*16 + fq*4 + t, col = n0 + wn4*64 + j*16 + fr.
// ---------------------------------------------------------------------------
__global__ __launch_bounds__(512, 2) void gemm_qkv_all8(
    const bf16_t* __restrict__ h_all, const bf16_t* __restrict__ Wb,
    const float* __restrict__ bq, const float* __restrict__ bk,
    const float* __restrict__ bv,
    bf16_t* __restrict__ q_all, bf16_t* __restrict__ k_all,
    bf16_t* __restrict__ v_all)
{
    __shared__ bf16_t lds8[8 * SL8];
    const int sel = blockIdx.z >> 3;
    const int b   = blockIdx.z & 7;
    const bf16_t* A = h_all + (size_t)b * NCb;
    const bf16_t* B = Wb + (size_t)sel * WSZ;
    const float* bias = (sel == 0) ? bq : (sel == 1) ? bk : bv;
    bf16_t* out = ((sel == 0) ? q_all : (sel == 1) ? k_all : v_all)
                + (size_t)b * NCb;
    const size_t m0 = (size_t)blockIdx.x * 256, n0 = (size_t)blockIdx.y * 256;

    f4v acc[8][4];
#pragma unroll
    for (int i = 0; i < 8; i++)
#pragma unroll
        for (int j = 0; j < 4; j++) acc[i][j] = (f4v){0.f, 0.f, 0.f, 0.f};

    gemm_core8(A, B, 512, 512, 512, m0, n0, lds8, acc);

    const int lane = threadIdx.x & 63, wave = threadIdx.x >> 6;
    const int wm2 = wave >> 2, wn4 = wave & 3;
    const int fr = lane & 15, fq = lane >> 4;

    if (sel < 2) {
#pragma unroll
        for (int ig = 0; ig < 8; ig++) {
            const int mb = (int)m0 + wm2 * 128 + ig * 16 + fq * 4;
#pragma unroll
            for (int j = 0; j < 4; j++) {
                const int n = (int)n0 + wn4 * 64 + j * 16 + fr;
                const float bn = bias[n];
#pragma unroll
                for (int t = 0; t < 4; t++)
                    out[(size_t)(mb + t) * 512 + n] =
                        (bf16_t)(acc[ig][j][t] + bn);
            }
        }
    } else {
#pragma unroll
        for (int ig = 0; ig < 8; ig++) {
            const int mb = (int)m0 + wm2 * 128 + ig * 16 + fq * 4;
#pragma unroll
            for (int j = 0; j < 4; j++) {
                const int n = (int)n0 + wn4 * 64 + j * 16 + fr;
                const float bn = bias[n];
                bf4v pk;
#pragma unroll
                for (int t = 0; t < 4; t++)
                    pk[t] = (bf16_t)(acc[ig][j][t] + bn);
                *(bf4v*)(out + (size_t)n * NN + mb) = pk;
            }
        }
    }
}

// QK^T for 2 or 4 batches: grid (16, 16, Z); z = batch offset within group.
__global__ __launch_bounds__(512, 2) void gemm_qkt8(
    const bf16_t* __restrict__ q_all, const bf16_t* __restrict__ k_all,
    bf16_t* __restrict__ S2b, int bp, float scale)
{
    __shared__ bf16_t lds8[8 * SL8];
    const int z = blockIdx.z;
    const bf16_t* A = q_all + (size_t)(bp + z) * NCb;
    const bf16_t* B = k_all + (size_t)(bp + z) * NCb;
    bf16_t* out = S2b + (size_t)z * NN * NN;
    const size_t m0 = (size_t)blockIdx.x * 256, n0 = (size_t)blockIdx.y * 256;

    f4v acc[8][4];
#pragma unroll
    for (int i = 0; i < 8; i++)
#pragma unroll
        for (int j = 0; j < 4; j++) acc[i][j] = (f4v){0.f, 0.f, 0.f, 0.f};

    gemm_core8(A, B, 512, 512, 512, m0, n0, lds8, acc);

    const int lane = threadIdx.x & 63, wave = threadIdx.x >> 6;
    const int wm2 = wave >> 2, wn4 = wave & 3;
    const int fr = lane & 15, fq = lane >> 4;
#pragma unroll
    for (int ig = 0; ig < 8; ig++) {
        const int mb = (int)m0 + wm2 * 128 + ig * 16 + fq * 4;
#pragma unroll
        for (int j = 0; j < 4; j++) {
            const int n = (int)n0 + wn4 * 64 + j * 16 + fr;
#pragma unroll
            for (int t = 0; t < 4; t++)
                out[(size_t)(mb + t) * NN + n] = (bf16_t)(acc[ig][j][t] * scale);
        }
    }
}

// PV for a PAIR (fallback tier 2): grid (16, 2, 8); z -> (slot:2, kslice:4).
__global__ __launch_bounds__(512, 2) void gemm_pv28(
    const bf16_t* __restrict__ S2b, const bf16_t* __restrict__ v_all,
    float* __restrict__ P, int bp)
{
    __shared__ bf16_t lds8[8 * SL8];
    const int slot = blockIdx.z >> 2;
    const int s    = blockIdx.z & 3;
    const int k0   = s * 1024;
    const bf16_t* A = S2b + (size_t)slot * NN * NN + k0;
    const bf16_t* B = v_all + (size_t)(bp + slot) * NCb + k0;
    float* out = P + ((size_t)slot * 4 + s) * NCb;
    const size_t m0 = (size_t)blockIdx.x * 256, n0 = (size_t)blockIdx.y * 256;

    f4v acc[8][4];
#pragma unroll
    for (int i = 0; i < 8; i++)
#pragma unroll
        for (int j = 0; j < 4; j++) acc[i][j] = (f4v){0.f, 0.f, 0.f, 0.f};

    gemm_core8(A, B, 1024, NN, NN, m0, n0, lds8, acc);

    const int lane = threadIdx.x & 63, wave = threadIdx.x >> 6;
    const int wm2 = wave >> 2, wn4 = wave & 3;
    const int fr = lane & 15, fq = lane >> 4;
#pragma unroll
    for (int ig = 0; ig < 8; ig++) {
        const int mb = (int)m0 + wm2 * 128 + ig * 16 + fq * 4;
#pragma unroll
        for (int j = 0; j < 4; j++) {
            const int n = (int)n0 + wn4 * 64 + j * 16 + fr;
#pragma unroll
            for (int t = 0; t < 4; t++)
                out[(size_t)(mb + t) * CC + n] = acc[ig][j][t];
        }
    }
}

// PV for a QUAD (main path): grid (16, 2, 8); z -> (slot:4, kslice:2).
// KS=2048 (NT=32, 4x amortization vs pair) ; P = 4 slots x 2 slices x 8 MB
// = 64 MB = d_out exactly. Halves P traffic vs pair-NS4.
__global__ __launch_bounds__(512, 2) void gemm_pv28q(
    const bf16_t* __restrict__ S4b, const bf16_t* __restrict__ v_all,
    float* __restrict__ P, int bp)
{
    __shared__ bf16_t lds8[8 * SL8];
    const int slot = blockIdx.z >> 1;          // 0..3 batch in quad
    const int s    = blockIdx.z & 1;           // 0..1 K-slice
    const int k0   = s * 2048;
    const bf16_t* A = S4b + (size_t)slot * NN * NN + k0;
    const bf16_t* B = v_all + (size_t)(bp + slot) * NCb + k0;
    float* out = P + ((size_t)slot * 2 + s) * NCb;
    const size_t m0 = (size_t)blockIdx.x * 256, n0 = (size_t)blockIdx.y * 256;

    f4v acc[8][4];
#pragma unroll
    for (int i = 0; i < 8; i++)
#pragma unroll
        for (int j = 0; j < 4; j++) acc[i][j] = (f4v){0.f, 0.f, 0.f, 0.f};

    gemm_core8(A, B, 2048, NN, NN, m0, n0, lds8, acc);

    const int lane = threadIdx.x & 63, wave = threadIdx.x >> 6;
    const int wm2 = wave >> 2, wn4 = wave & 3;
    const int fr = lane & 15, fq = lane >> 4;
#pragma unroll
    for (int ig = 0; ig < 8; ig++) {
        const int mb = (int)m0 + wm2 * 128 + ig * 16 + fq * 4;
#pragma unroll
        for (int j = 0; j < 4; j++) {
            const int n = (int)n0 + wn4 * 64 + j * 16 + fr;
#pragma unroll
            for (int t = 0; t < 4; t++)
                out[(size_t)(mb + t) * CC + n] = acc[ig][j][t];
        }
    }
}

__global__ __launch_bounds__(512, 2) void gemm_out_all8(
    const bf16_t* __restrict__ Oall, const bf16_t* __restrict__ Wo,
    float* __restrict__ outg, const float* __restrict__ bo,
    const float* __restrict__ x)
{
    __shared__ bf16_t lds8[8 * SL8];
    const int b = blockIdx.z;
    const bf16_t* A = Oall + (size_t)b * NCb;
    float* out = outg + (size_t)b * CC * NN;
    const float* resid = x + (size_t)b * CC * NN;
    const size_t m0 = (size_t)blockIdx.x * 256, n0 = (size_t)blockIdx.y * 256;

    f4v acc[8][4];
#pragma unroll
    for (int i = 0; i < 8; i++)
#pragma unroll
        for (int j = 0; j < 4; j++) acc[i][j] = (f4v){0.f, 0.f, 0.f, 0.f};

    gemm_core8(A, Wo, 512, 512, 512, m0, n0, lds8, acc);

    const int lane = threadIdx.x & 63, wave = threadIdx.x >> 6;
    const int wm2 = wave >> 2, wn4 = wave & 3;
    const int fr = lane & 15, fq = lane >> 4;
#pragma unroll
    for (int ig = 0; ig < 8; ig++) {
        const int mb = (int)m0 + wm2 * 128 + ig * 16 + fq * 4;
#pragma unroll
        for (int j = 0; j < 4; j++) {
            const int n = (int)n0 + wn4 * 64 + j * 16 + fr;
            const float bn = bo[n];
            float4 rq = *(const float4*)(resid + (size_t)n * NN + mb);
            float4 o4;
            o4.x = acc[ig][j][0] + bn + rq.x;
            o4.y = acc[ig][j][1] + bn + rq.y;
            o4.z = acc[ig][j][2] + bn + rq.z;
            o4.w = acc[ig][j][3] + bn + rq.w;
            *(float4*)(out + (size_t)n * NN + mb) = o4;
        }
    }
}

// ---------------------------------------------------------------------------
// Reduce fp32 partials -> bf16 O. Pair variant (4 partials) and quad (2).
// ---------------------------------------------------------------------------
__global__ __launch_bounds__(256) void pv_reduce2(const float* __restrict__ P,
                                                  bf16_t* __restrict__ O_all,
                                                  int bp)
{
    const int slot = blockIdx.y;
    const size_t i = ((size_t)blockIdx.x * 256 + threadIdx.x) * 4;
    const float* Ps = P + (size_t)slot * 4 * NCb;
    float4 sv = *(const float4*)(Ps + i);
#pragma unroll
    for (int z = 1; z < 4; z++) {
        float4 t = *(const float4*)(Ps + (size_t)z * NCb + i);
        sv.x += t.x; sv.y += t.y; sv.z += t.z; sv.w += t.w;
    }
    bf4v o;
    o[0] = (bf16_t)sv.x; o[1] = (bf16_t)sv.y;
    o[2] = (bf16_t)sv.z; o[3] = (bf16_t)sv.w;
    *(bf4v*)(O_all + (size_t)(bp + slot) * NCb + i) = o;
}

__global__ __launch_bounds__(256) void pv_reduce2q(const float* __restrict__ P,
                                                   bf16_t* __restrict__ O_all,
                                                   int bp)
{
    const int slot = blockIdx.y;               // 0..3
    const size_t i = ((size_t)blockIdx.x * 256 + threadIdx.x) * 4;
    const float* Ps = P + (size_t)slot * 2 * NCb;
    float4 a = *(const float4*)(Ps + i);
    float4 b = *(const float4*)(Ps + (size_t)NCb + i);
    bf4v o;
    o[0] = (bf16_t)(a.x + b.x); o[1] = (bf16_t)(a.y + b.y);
    o[2] = (bf16_t)(a.z + b.z); o[3] = (bf16_t)(a.w + b.w);
    *(bf4v*)(O_all + (size_t)(bp + slot) * NCb + i) = o;
}

// ---------------------------------------------------------------------------
// Row softmax over S (rows x 4096 bf16), in place. 1 wave per row.
// ---------------------------------------------------------------------------
__global__ __launch_bounds__(256) void softmax_kernel(bf16_t* __restrict__ S)
{
    const int wave = threadIdx.x >> 6, lane = threadIdx.x & 63;
    const size_t row = (size_t)blockIdx.x * 4 + wave;
    bf16_t* p = S + row * NN;
    float f[64];
    float mx = -1e30f;
#pragma unroll
    for (int c = 0; c < 8; c++) {
        bf8v v = ((const bf8v*)p)[c * 64 + lane];
#pragma unroll
        for (int j = 0; j < 8; j++) {
            f[c * 8 + j] = (float)v[j];
            mx = fmaxf(mx, f[c * 8 + j]);
        }
    }
#pragma unroll
    for (int off = 32; off > 0; off >>= 1) mx = fmaxf(mx, __shfl_xor(mx, off));
    float sum = 0.f;
#pragma unroll
    for (int i = 0; i < 64; i++) { f[i] = expf(f[i] - mx); sum += f[i]; }
#pragma unroll
    for (int off = 32; off > 0; off >>= 1) sum += __shfl_xor(sum, off);
    const float inv = 1.f / sum;
#pragma unroll
    for (int c = 0; c < 8; c++) {
        bf8v o;
#pragma unroll
        for (int j = 0; j < 8; j++) o[j] = (bf16_t)(f[c * 8 + j] * inv);
        ((bf8v*)p)[c * 64 + lane] = o;
    }
}

// ---------------------------------------------------------------------------
extern "C" void kernel_launch(void* const* d_in, const int* in_sizes, int n_in,
                              void* d_out, int out_size, void* d_ws, size_t ws_size,
                              hipStream_t stream)
{
    const float* x  = (const float*)d_in[0];
    const float* gw = (const float*)d_in[1];
    const float* gb = (const float*)d_in[2];
    const float* Wq = (const float*)d_in[3];
    const float* bq = (const float*)d_in[4];
    const float* Wk = (const float*)d_in[5];
    const float* bk = (const float*)d_in[6];
    const float* Wv = (const float*)d_in[7];
    const float* bv = (const float*)d_in[8];
    const float* Wo = (const float*)d_in[9];
    const float* bo = (const float*)d_in[10];
    float* out = (float*)d_out;          // *** fp32 output ***

    bool ok = (n_in == 11) && (out_size == BB * CC * NN) &&
              (in_sizes[0] == BB * CC * NN) &&
              (in_sizes[1] == CC) && (in_sizes[2] == CC) &&
              (in_sizes[3] == WSZ) && (in_sizes[4] == CC) &&
              (in_sizes[5] == WSZ) && (in_sizes[6] == CC) &&
              (in_sizes[7] == WSZ) && (in_sizes[8] == CC) &&
              (in_sizes[9] == WSZ) && (in_sizes[10] == CC);
    if (!ok) { diag_out<<<dim3(1), 64, 0, stream>>>(out, FLG_SIZES); return; }

    const float sc = 0.044194173824159216f;           // 512^-0.5

    // ---- common small buffers ----
    bf16_t* Wb    = (bf16_t*)d_ws;                     // 4*WSZ bf16 (2 MB)
    float*  stats = (float*)(Wb + (size_t)4 * WSZ);    // 1024 floats
    double* part  = (double*)(stats + 1024);           // 2048 doubles
    bf16_t* base  = (bf16_t*)(part + 2048);
    const size_t head = (size_t)4 * WSZ * 2 + 1024 * 4 + 2048 * 8;

    const size_t sfull = (size_t)NN * NN * 2;

    cvt_w<<<dim3(256), 256, 0, stream>>>(Wq, Wk, Wv, Wo, Wb);
    gn_stats_part<<<dim3(1024), 256, 0, stream>>>(x, part);
    gn_stats_fin<<<dim3(1), 256, 0, stream>>>(part, stats);

    // ---- tier 1: QUAD-batched path (needs ~258 MiB ws; P lives in d_out) ----
    if (ws_size >= head + (size_t)4 * BB * NCb * 2 + 4 * sfull) {
        bf16_t* h_all = base;                          // (B,N,C)
        bf16_t* q_all = h_all + (size_t)BB * NCb;
        bf16_t* k_all = q_all + (size_t)BB * NCb;
        bf16_t* v_all = k_all + (size_t)BB * NCb;      // (B,C,N)
        bf16_t* S4    = v_all + (size_t)BB * NCb;      // 4 batches of S (128 MB)
        float*  P     = out;                           // d_out scratch (64 MB)
        bf16_t* O_all = h_all;                         // overlay: h dead post-qkv

        gn_apply_all<<<dim3(512, 8), 256, 0, stream>>>(x, gw, gb, stats, h_all);
        gemm_qkv_all8<<<dim3(16, 2, 24), 512, 0, stream>>>(
            h_all, Wb, bq, bk, bv, q_all, k_all, v_all);

        for (int bp = 0; bp < BB; bp += 4) {
            gemm_qkt8<<<dim3(16, 16, 4), 512, 0, stream>>>(
                q_all, k_all, S4, bp, sc);
            softmax_kernel<<<dim3(4 * NN / 4), 256, 0, stream>>>(S4);
            gemm_pv28q<<<dim3(16, 2, 8), 512, 0, stream>>>(S4, v_all, P, bp);
            pv_reduce2q<<<dim3(NCb / 1024, 4), 256, 0, stream>>>(P, O_all, bp);
        }

        gemm_out_all8<<<dim3(16, 2, 8), 512, 0, stream>>>(
            O_all, Wb + (size_t)3 * WSZ, out, bo, x);
        return;
    }

    // ---- tier 2: PAIR-batched path (needs 194 MiB ws) ----
    if (ws_size >= head + (size_t)4 * BB * NCb * 2 + 2 * sfull) {
        bf16_t* h_all = base;
        bf16_t* q_all = h_all + (size_t)BB * NCb;
        bf16_t* k_all = q_all + (size_t)BB * NCb;
        bf16_t* v_all = k_all + (size_t)BB * NCb;
        bf16_t* S2    = v_all + (size_t)BB * NCb;
        float*  P     = out;
        bf16_t* O_all = h_all;

        gn_apply_all<<<dim3(512, 8), 256, 0, stream>>>(x, gw, gb, stats, h_all);
        gemm_qkv_all8<<<dim3(16, 2, 24), 512, 0, stream>>>(
            h_all, Wb, bq, bk, bv, q_all, k_all, v_all);

        for (int bp = 0; bp < BB; bp += 2) {
            gemm_qkt8<<<dim3(16, 16, 2), 512, 0, stream>>>(
                q_all, k_all, S2, bp, sc);
            softmax_kernel<<<dim3(2 * NN / 4), 256, 0, stream>>>(S2);
            gemm_pv28<<<dim3(16, 2, 8), 512, 0, stream>>>(S2, v_all, P, bp);
            pv_reduce2<<<dim3(NCb / 1024, 2), 256, 0, stream>>>(P, O_all, bp);
        }

        gemm_out_all8<<<dim3(16, 2, 8), 512, 0, stream>>>(
            O_all, Wb + (size_t)3 * WSZ, out, bo, x);
        return;
    }

    // ---- tier 3: per-batch fallback (small workspace), old 4-wave kernels ----
    bf16_t* h = base;                                  // per-batch (N,C)
    bf16_t* q = h + (size_t)NCb;
    bf16_t* k = q + (size_t)NCb;
    bf16_t* v = k + (size_t)NCb;                       // (C,N)
    bf16_t* S = v + (size_t)NCb;
    bf16_t* O = h;
    const size_t fixed = head + (size_t)4 * NCb * 2;

    if (ws_size < fixed + (size_t)128 * NN * 2) {
        diag_out<<<dim3(1), 64, 0, stream>>>(out, FLG_WS); return;
    }

    int NS = 0;
    if (ws_size >= fixed + sfull + (size_t)8 * NCb * 4)      NS = 8;
    else if (ws_size >= fixed + sfull + (size_t)4 * NCb * 4) NS = 4;
    else if (ws_size >= fixed + sfull + (size_t)2 * NCb * 4) NS = 2;

    if (NS) {
        float* P = (float*)(S + (size_t)NN * NN);
        for (int b = 0; b < BB; b++) {
            const float* xb   = x   + (size_t)b * CC * NN;
            float*       outb = out + (size_t)b * CC * NN;

            gn_apply<<<dim3(512), 256, 0, stream>>>(xb, gw, gb, stats, h, b * 32);
            gemm_qkv<<<dim3(32, 2, 3), 256, 0, stream>>>(h, Wb, bq, bk, bv, q, k, v);

            gemm_bt<0><<<dim3(32, 16), 256, 0, stream>>>(
                q, k, S, nullptr, nullptr, sc, 512, 512, 512, 4096);
            softmax_kernel<<<dim3(NN / 4), 256, 0, stream>>>(S);

            gemm_pv_split<<<dim3(32, 2, NS), 256, 0, stream>>>(S, v, P, NN / NS);
            pv_reduce<<<dim3(NCb / 1024), 256, 0, stream>>>(P, O, NS);

            gemm_bt<2><<<dim3(32, 2), 256, 0, stream>>>(
                O, Wb + (size_t)3 * WSZ, outb, bo, xb, 1.f,
                512, 512, 512, 4096);
        }
        return;
    }

    int CH = 128;
    while (CH < NN && fixed + (size_t)(CH * 2) * NN * 2 <= ws_size) CH *= 2;

    for (int b = 0; b < BB; b++) {
        const float* xb   = x   + (size_t)b * CC * NN;
        float*       outb = out + (size_t)b * CC * NN;

        gn_apply<<<dim3(512), 256, 0, stream>>>(xb, gw, gb, stats, h, b * 32);
        gemm_qkv<<<dim3(32, 2, 3), 256, 0, stream>>>(h, Wb, bq, bk, bv, q, k, v);

        for (int r0 = 0; r0 < NN; r0 += CH) {
            gemm_bt<0><<<dim3(CH / 128, 16), 256, 0, stream>>>(
                q + (size_t)r0 * CC, k, S, nullptr, nullptr, sc,
                512, 512, 512, 4096);
            softmax_kernel<<<dim3(CH / 4), 256, 0, stream>>>(S);
            gemm_bt<0><<<dim3(CH / 128, 2), 256, 0, stream>>>(
                S, v, O + (size_t)r0 * CC, nullptr, nullptr, 1.f,
                4096, 4096, 4096, 512);
        }

        gemm_bt<2><<<dim3(32, 2), 256, 0, stream>>>(
            O, Wb + (size_t)3 * WSZ, outb, bo, xb, 1.f,
            512, 512, 512, 4096);
    }
}